// Round 1
// baseline (259.549 us; speedup 1.0000x reference)
//
#include <hip/hip_runtime.h>
#include <math.h>

constexpr int D = 128;       // in_channels
constexpr int B = 512;       // batch_size (graphs)
constexpr int STEPS = 3;
constexpr int NW_IH = 3 * D * 2 * D;   // 98304 elems, Wih [3D][2D]
constexpr int NW_HH = 3 * D * D;       // 49152 elems, Whh [3D][D]

__device__ __forceinline__ float sigmoidf_(float x) { return 1.f / (1.f + __expf(-x)); }
// bf16 pair unpack from a uint: low halfword / high halfword -> float (exact)
__device__ __forceinline__ float bflo(unsigned int u) { return __uint_as_float(u << 16); }
__device__ __forceinline__ float bfhi(unsigned int u) { return __uint_as_float(u & 0xffff0000u); }
__device__ __forceinline__ unsigned short f2bf_rn(float f) {
    unsigned int u = __float_as_uint(f);
    u += 0x7fffu + ((u >> 16) & 1u);    // round-to-nearest-even
    return (unsigned short)(u >> 16);
}

// ---------------------------------------------------------------------------
// K0 (prep): weights fp32 -> bf16 (RN), plus segment bounds via binary search
// on sorted batch[] (seg[g] = first index with batch[i] >= g).
// ---------------------------------------------------------------------------
__global__ __launch_bounds__(256) void k_prep(const float* __restrict__ Wih,
        const float* __restrict__ Whh, const int* __restrict__ batch, int n,
        unsigned short* __restrict__ wih_bf, unsigned short* __restrict__ whh_bf,
        int* __restrict__ seg) {
    int i = blockIdx.x * blockDim.x + threadIdx.x;
    if (i < NW_IH) wih_bf[i] = f2bf_rn(Wih[i]);
    else if (i < NW_IH + NW_HH) whh_bf[i - NW_IH] = f2bf_rn(Whh[i - NW_IH]);
    if (i <= B) {
        int lo = 0, hi = n;
        while (lo < hi) { int mid = (lo + hi) >> 1; if (batch[mid] < i) lo = mid + 1; else hi = mid; }
        seg[i] = lo;
    }
}

// ---------------------------------------------------------------------------
// K1 (fused Set2Set): one block per graph, 1024 threads, all 3 steps inside.
// Latency-oriented restructure vs previous version:
//   * Attention: 16-lane node-groups (4 nodes / wave-iter), 2xfloat4 per lane,
//     4-shfl reduce shared by 4 nodes, hand-unrolled x2 -> 4 loads in flight.
//   * GRU: pair-split (768 threads, 2 per gate row -> half the serial chain),
//     ds_read_b128 for q/h instead of 384 scalar ds_read_b32 per thread.
//   * Softmax combine: every wave redundantly butterfly-reduces the 64 (m,l)
//     partials -> no tid0 serial section, one less barrier, 1/L folded into
//     the per-lane rescale.
// __launch_bounds__(1024,8): VGPR<=64 -> 2 blocks/CU = 32 waves/CU.
// ---------------------------------------------------------------------------
__global__ __launch_bounds__(1024, 8) void k_set2set(
        const float* __restrict__ x,
        const unsigned short* __restrict__ wih_bf,
        const unsigned short* __restrict__ whh_bf,
        const float* __restrict__ bih, const float* __restrict__ bhh,
        const int* __restrict__ seg, float* __restrict__ out) {
    __shared__ __align__(16) float s_q[2 * D];    // q_star for this graph: [q | r]
    __shared__ __align__(16) float s_h[D];
    __shared__ float s_gi[3 * D], s_gh[3 * D];
    __shared__ float sm[64], sl[64];
    __shared__ __align__(16) float rpart[16][D];  // 8 KB

    const int b = blockIdx.x;
    const int tid = threadIdx.x;
    const int start = seg[b], end = seg[b + 1];
    const int g = tid >> 4;               // node-group id 0..63 (16 lanes each)
    const int s = tid & 15;               // sublane: owns columns s*8 .. s*8+7

    if (tid < 2 * D) s_q[tid] = 0.f;
    if (tid < D) s_h[tid] = 0.f;
    __syncthreads();

    for (int step = 0; step < STEPS; ++step) {
        // ---- GRU gate rows: 2 threads per row, each does half the columns ----
        if (tid < 768) {
            const int row  = tid >> 1;
            const int half = tid & 1;
            float gi = half ? 0.f : bih[row];
            float gh = half ? bhh[row] : 0.f;
            const float4* q4 = (const float4*)s_q;
            const float4* h4 = (const float4*)s_h;
            const uint4* wr = (const uint4*)(wih_bf + (size_t)row * (2 * D)) + half * 16;
#pragma unroll 4
            for (int c = 0; c < 16; ++c) {          // 128 cols of Wih
                uint4 w = wr[c];
                float4 qa = q4[half * 32 + c * 2];
                float4 qb = q4[half * 32 + c * 2 + 1];
                gi = fmaf(bflo(w.x), qa.x, gi); gi = fmaf(bfhi(w.x), qa.y, gi);
                gi = fmaf(bflo(w.y), qa.z, gi); gi = fmaf(bfhi(w.y), qa.w, gi);
                gi = fmaf(bflo(w.z), qb.x, gi); gi = fmaf(bfhi(w.z), qb.y, gi);
                gi = fmaf(bflo(w.w), qb.z, gi); gi = fmaf(bfhi(w.w), qb.w, gi);
            }
            const uint4* vr = (const uint4*)(whh_bf + (size_t)row * D) + half * 8;
#pragma unroll 4
            for (int c = 0; c < 8; ++c) {           // 64 cols of Whh
                uint4 w = vr[c];
                float4 ha = h4[half * 16 + c * 2];
                float4 hb = h4[half * 16 + c * 2 + 1];
                gh = fmaf(bflo(w.x), ha.x, gh); gh = fmaf(bfhi(w.x), ha.y, gh);
                gh = fmaf(bflo(w.y), ha.z, gh); gh = fmaf(bfhi(w.y), ha.w, gh);
                gh = fmaf(bflo(w.z), hb.x, gh); gh = fmaf(bfhi(w.z), hb.y, gh);
                gh = fmaf(bflo(w.w), hb.z, gh); gh = fmaf(bfhi(w.w), hb.w, gh);
            }
            gi += __shfl_xor(gi, 1, 64);
            gh += __shfl_xor(gh, 1, 64);
            if (!half) { s_gi[row] = gi; s_gh[row] = gh; }
        }
        __syncthreads();
        // ---- GRU epilogue ----
        if (tid < D) {
            const int t = tid;
            float r  = sigmoidf_(s_gi[t] + s_gh[t]);
            float z  = sigmoidf_(s_gi[D + t] + s_gh[D + t]);
            float nn = tanhf(s_gi[2 * D + t] + r * s_gh[2 * D + t]);
            float hn = (1.f - z) * nn + z * s_h[t];
            s_h[t] = hn;
            s_q[t] = hn;                  // q part of q_star
        }
        __syncthreads();

        // ---- flash attention: group of 16 lanes handles one node/iter ----
        const float4 q0 = ((const float4*)s_h)[s * 2];
        const float4 q1 = ((const float4*)s_h)[s * 2 + 1];
        float m_run = -INFINITY, l_run = 0.f;
        float4 acc0 = {0.f, 0.f, 0.f, 0.f};
        float4 acc1 = {0.f, 0.f, 0.f, 0.f};

        auto process = [&](const float4& v0, const float4& v1) {
            float p;
            p = v0.x * q0.x;
            p = fmaf(v0.y, q0.y, p); p = fmaf(v0.z, q0.z, p); p = fmaf(v0.w, q0.w, p);
            p = fmaf(v1.x, q1.x, p); p = fmaf(v1.y, q1.y, p);
            p = fmaf(v1.z, q1.z, p); p = fmaf(v1.w, q1.w, p);
            p += __shfl_xor(p, 1, 64);
            p += __shfl_xor(p, 2, 64);
            p += __shfl_xor(p, 4, 64);
            p += __shfl_xor(p, 8, 64);            // e, uniform over the 16-lane group
            float nm = fmaxf(m_run, p);
            float sc = __expf(m_run - nm);        // 0 on first iter
            float a  = __expf(p - nm);
            l_run = fmaf(l_run, sc, a);
            acc0.x = fmaf(acc0.x, sc, a * v0.x);
            acc0.y = fmaf(acc0.y, sc, a * v0.y);
            acc0.z = fmaf(acc0.z, sc, a * v0.z);
            acc0.w = fmaf(acc0.w, sc, a * v0.w);
            acc1.x = fmaf(acc1.x, sc, a * v1.x);
            acc1.y = fmaf(acc1.y, sc, a * v1.y);
            acc1.z = fmaf(acc1.z, sc, a * v1.z);
            acc1.w = fmaf(acc1.w, sc, a * v1.w);
            m_run = nm;
        };

        for (int n0 = start + g; n0 < end; n0 += 128) {
            const int n1 = n0 + 64;
            const float* p0 = x + (size_t)n0 * D + s * 8;
            float4 a0 = *(const float4*)p0;
            float4 a1 = *(const float4*)(p0 + 4);
            if (n1 < end) {
                const float* p1 = x + (size_t)n1 * D + s * 8;
                float4 b0 = *(const float4*)p1;
                float4 b1 = *(const float4*)(p1 + 4);
                process(a0, a1);
                process(b0, b1);
            } else {
                process(a0, a1);
            }
        }

        if (s == 0) { sm[g] = m_run; sl[g] = l_run; }
        __syncthreads();

        // ---- every wave redundantly combines the 64 (m,l) partials ----
        {
            const float mv = sm[tid & 63];
            const float lv = sl[tid & 63];
            float M = mv;
            M = fmaxf(M, __shfl_xor(M, 1, 64));
            M = fmaxf(M, __shfl_xor(M, 2, 64));
            M = fmaxf(M, __shfl_xor(M, 4, 64));
            M = fmaxf(M, __shfl_xor(M, 8, 64));
            M = fmaxf(M, __shfl_xor(M, 16, 64));
            M = fmaxf(M, __shfl_xor(M, 32, 64));
            float term = (mv == -INFINITY) ? 0.f : lv * __expf(mv - M);
            term += __shfl_xor(term, 1, 64);
            term += __shfl_xor(term, 2, 64);
            term += __shfl_xor(term, 4, 64);
            term += __shfl_xor(term, 8, 64);
            term += __shfl_xor(term, 16, 64);
            term += __shfl_xor(term, 32, 64);
            const float inv = 1.f / (term + 1e-16f);
            // rescale this group's acc to the global max, fold in 1/L
            const float fac = (m_run == -INFINITY) ? 0.f : __expf(m_run - M) * inv;
            acc0.x *= fac; acc0.y *= fac; acc0.z *= fac; acc0.w *= fac;
            acc1.x *= fac; acc1.y *= fac; acc1.z *= fac; acc1.w *= fac;
        }
        // ---- sum the 4 groups within each wave (lanes s, s^16, s^32, s^48
        //      hold the same columns) ----
        acc0.x += __shfl_xor(acc0.x, 16, 64); acc0.y += __shfl_xor(acc0.y, 16, 64);
        acc0.z += __shfl_xor(acc0.z, 16, 64); acc0.w += __shfl_xor(acc0.w, 16, 64);
        acc1.x += __shfl_xor(acc1.x, 16, 64); acc1.y += __shfl_xor(acc1.y, 16, 64);
        acc1.z += __shfl_xor(acc1.z, 16, 64); acc1.w += __shfl_xor(acc1.w, 16, 64);
        acc0.x += __shfl_xor(acc0.x, 32, 64); acc0.y += __shfl_xor(acc0.y, 32, 64);
        acc0.z += __shfl_xor(acc0.z, 32, 64); acc0.w += __shfl_xor(acc0.w, 32, 64);
        acc1.x += __shfl_xor(acc1.x, 32, 64); acc1.y += __shfl_xor(acc1.y, 32, 64);
        acc1.z += __shfl_xor(acc1.z, 32, 64); acc1.w += __shfl_xor(acc1.w, 32, 64);

        const int wv = tid >> 6;          // wave id 0..15
        if ((tid & 63) < 16) {
            float4* dst = (float4*)&rpart[wv][s * 8];
            dst[0] = acc0; dst[1] = acc1;
        }
        __syncthreads();
        if (tid < D) {
            float v = 0.f;
#pragma unroll
            for (int w = 0; w < 16; ++w) v += rpart[w][tid];
            s_q[D + tid] = v;             // r part of q_star (already /L)
        }
        __syncthreads();                  // s_q complete for next GRU / output
    }

    // ---- write q_star row (s_q is exactly [q | r]) ----
    if (tid < 2 * D) out[(size_t)b * (2 * D) + tid] = s_q[tid];
}

// ---------------------------------------------------------------------------
extern "C" void kernel_launch(void* const* d_in, const int* in_sizes, int n_in,
                              void* d_out, int out_size, void* d_ws, size_t ws_size,
                              hipStream_t stream) {
    const float* x    = (const float*)d_in[0];
    const int*   batch= (const int*)d_in[1];
    // d_in[2] = batch_size scalar (fixed at B=512 compile time)
    const float* Wih  = (const float*)d_in[3];
    const float* Whh  = (const float*)d_in[4];
    const float* bih  = (const float*)d_in[5];
    const float* bhh  = (const float*)d_in[6];
    const int n = in_sizes[0] / D;        // 200000

    // workspace: seg (4 KB pad) | wih_bf (192 KB) | whh_bf (96 KB)
    char* ws = (char*)d_ws;
    int* seg = (int*)ws;
    unsigned short* wih_bf = (unsigned short*)(ws + 4096);
    unsigned short* whh_bf = (unsigned short*)(ws + 4096 + (size_t)NW_IH * 2);

    const int total = NW_IH + NW_HH;      // 147456 >= B+1, covers seg too
    k_prep<<<(total + 255) / 256, 256, 0, stream>>>(Wih, Whh, batch, n, wih_bf, whh_bf, seg);
    k_set2set<<<B, 1024, 0, stream>>>(x, wih_bf, whh_bf, bih, bhh, seg, (float*)d_out);
}

// Round 2
// 236.152 us; speedup vs baseline: 1.0991x; 1.0991x over previous
//
#include <hip/hip_runtime.h>
#include <math.h>

constexpr int D = 128;       // in_channels
constexpr int B = 512;       // batch_size (graphs)
constexpr int STEPS = 3;
constexpr int NW_IH = 3 * D * 2 * D;   // 98304 elems, Wih [3D][2D]
constexpr int NW_HH = 3 * D * D;       // 49152 elems, Whh [3D][D]

__device__ __forceinline__ float sigmoidf_(float x) { return 1.f / (1.f + __expf(-x)); }
// bf16 pair unpack from a uint: low halfword / high halfword -> float (exact)
__device__ __forceinline__ float bflo(unsigned int u) { return __uint_as_float(u << 16); }
__device__ __forceinline__ float bfhi(unsigned int u) { return __uint_as_float(u & 0xffff0000u); }
__device__ __forceinline__ unsigned short f2bf_rn(float f) {
    unsigned int u = __float_as_uint(f);
    u += 0x7fffu + ((u >> 16) & 1u);    // round-to-nearest-even
    return (unsigned short)(u >> 16);
}
__device__ __forceinline__ float4 ld4(const float* p) { return *(const float4*)p; }

// ---------------------------------------------------------------------------
// K0 (prep): weights fp32 -> bf16 (RN), plus segment bounds via binary search
// on sorted batch[] (seg[g] = first index with batch[i] >= g).
// ---------------------------------------------------------------------------
__global__ __launch_bounds__(256) void k_prep(const float* __restrict__ Wih,
        const float* __restrict__ Whh, const int* __restrict__ batch, int n,
        unsigned short* __restrict__ wih_bf, unsigned short* __restrict__ whh_bf,
        int* __restrict__ seg) {
    int i = blockIdx.x * blockDim.x + threadIdx.x;
    if (i < NW_IH) wih_bf[i] = f2bf_rn(Wih[i]);
    else if (i < NW_IH + NW_HH) whh_bf[i - NW_IH] = f2bf_rn(Whh[i - NW_IH]);
    if (i <= B) {
        int lo = 0, hi = n;
        while (lo < hi) { int mid = (lo + hi) >> 1; if (batch[mid] < i) lo = mid + 1; else hi = mid; }
        seg[i] = lo;
    }
}

// ---------------------------------------------------------------------------
// K1 (fused Set2Set): one block of 256 threads (4 waves) per graph.
// Rationale vs previous 1024-thread version (latency-bound, spilling):
//   * __launch_bounds__(256,2): grid gives only 2 blocks/CU (512 blocks/256
//     CUs) so occupancy is 8 waves/CU regardless -> declare it, get a 256
//     VGPR budget -> ZERO spills (prev: 25 MB of scratch writes on the
//     attention dep chain).
//   * 16 node-groups (16 lanes each) -> ~6 full trips of 4 nodes/group:
//     a real loop, hand double-buffered (two named Trip register sets,
//     8 b128 loads in flight per lane).
//   * Trip 0's x-loads are issued BEFORE the GRU phase (x is step-invariant)
//     so HBM latency hides under the GRU matvec.
//   * Batched online softmax: one rescale + 5 exp per 4 nodes.
//   * Barriers sync 4 waves, not 16.
// ---------------------------------------------------------------------------
struct Trip { float4 a0, a1, b0, b1, c0, c1, d0, d1; };

__global__ __launch_bounds__(256, 2) void k_set2set(
        const float* __restrict__ x,
        const unsigned short* __restrict__ wih_bf,
        const unsigned short* __restrict__ whh_bf,
        const float* __restrict__ bih, const float* __restrict__ bhh,
        const int* __restrict__ seg, float* __restrict__ out) {
    __shared__ __align__(16) float s_q[2 * D];    // q_star: [q | r]
    __shared__ __align__(16) float s_h[D];
    __shared__ float s_gi[3 * D], s_gh[3 * D];
    __shared__ float sm[16], sl[16];
    __shared__ __align__(16) float rpart[4][D];   // 2 KB

    const int b = blockIdx.x;
    const int tid = threadIdx.x;
    const int start = seg[b], end = seg[b + 1];
    const int g = tid >> 4;               // node-group id 0..15
    const int s = tid & 15;               // sublane: owns columns s*8 .. s*8+7

    if (tid < 2 * D) s_q[tid] = 0.f;
    if (tid < D) s_h[tid] = 0.f;
    __syncthreads();

    const int len = end - start;
    const int F = len >> 6;               // full 64-node trips
    // lane's base pointer: node (start+g), columns s*8..s*8+7
    const float* xb = x + (size_t)(start + g) * D + s * 8;

    float m_run, l_run;
    float4 acc0, acc1;
    float4 q0, q1;

    auto load_trip = [&](Trip& T, int t) {
        const float* p = xb + (size_t)t * (64 * D);
        T.a0 = ld4(p);            T.a1 = ld4(p + 4);
        T.b0 = ld4(p + 16 * D);   T.b1 = ld4(p + 16 * D + 4);
        T.c0 = ld4(p + 32 * D);   T.c1 = ld4(p + 32 * D + 4);
        T.d0 = ld4(p + 48 * D);   T.d1 = ld4(p + 48 * D + 4);
    };
    auto dot8 = [&](const float4& lo, const float4& hi) {
        float p = lo.x * q0.x;
        p = fmaf(lo.y, q0.y, p); p = fmaf(lo.z, q0.z, p); p = fmaf(lo.w, q0.w, p);
        p = fmaf(hi.x, q1.x, p); p = fmaf(hi.y, q1.y, p);
        p = fmaf(hi.z, q1.z, p); p = fmaf(hi.w, q1.w, p);
        return p;
    };
    auto compute = [&](const Trip& T) {
        float p0 = dot8(T.a0, T.a1);
        float p1 = dot8(T.b0, T.b1);
        float p2 = dot8(T.c0, T.c1);
        float p3 = dot8(T.d0, T.d1);
        p0 += __shfl_xor(p0, 1, 64); p1 += __shfl_xor(p1, 1, 64);
        p2 += __shfl_xor(p2, 1, 64); p3 += __shfl_xor(p3, 1, 64);
        p0 += __shfl_xor(p0, 2, 64); p1 += __shfl_xor(p1, 2, 64);
        p2 += __shfl_xor(p2, 2, 64); p3 += __shfl_xor(p3, 2, 64);
        p0 += __shfl_xor(p0, 4, 64); p1 += __shfl_xor(p1, 4, 64);
        p2 += __shfl_xor(p2, 4, 64); p3 += __shfl_xor(p3, 4, 64);
        p0 += __shfl_xor(p0, 8, 64); p1 += __shfl_xor(p1, 8, 64);
        p2 += __shfl_xor(p2, 8, 64); p3 += __shfl_xor(p3, 8, 64);
        float nm = fmaxf(m_run, fmaxf(fmaxf(p0, p1), fmaxf(p2, p3)));
        float sc = __expf(m_run - nm);            // 0 on first trip
        float e0 = __expf(p0 - nm), e1 = __expf(p1 - nm);
        float e2 = __expf(p2 - nm), e3 = __expf(p3 - nm);
        l_run = fmaf(l_run, sc, (e0 + e1) + (e2 + e3));
        acc0.x = fmaf(acc0.x, sc, fmaf(e0, T.a0.x, fmaf(e1, T.b0.x, fmaf(e2, T.c0.x, e3 * T.d0.x))));
        acc0.y = fmaf(acc0.y, sc, fmaf(e0, T.a0.y, fmaf(e1, T.b0.y, fmaf(e2, T.c0.y, e3 * T.d0.y))));
        acc0.z = fmaf(acc0.z, sc, fmaf(e0, T.a0.z, fmaf(e1, T.b0.z, fmaf(e2, T.c0.z, e3 * T.d0.z))));
        acc0.w = fmaf(acc0.w, sc, fmaf(e0, T.a0.w, fmaf(e1, T.b0.w, fmaf(e2, T.c0.w, e3 * T.d0.w))));
        acc1.x = fmaf(acc1.x, sc, fmaf(e0, T.a1.x, fmaf(e1, T.b1.x, fmaf(e2, T.c1.x, e3 * T.d1.x))));
        acc1.y = fmaf(acc1.y, sc, fmaf(e0, T.a1.y, fmaf(e1, T.b1.y, fmaf(e2, T.c1.y, e3 * T.d1.y))));
        acc1.z = fmaf(acc1.z, sc, fmaf(e0, T.a1.z, fmaf(e1, T.b1.z, fmaf(e2, T.c1.z, e3 * T.d1.z))));
        acc1.w = fmaf(acc1.w, sc, fmaf(e0, T.a1.w, fmaf(e1, T.b1.w, fmaf(e2, T.c1.w, e3 * T.d1.w))));
        m_run = nm;
    };
    auto one_node = [&](const float4& v0, const float4& v1) {
        float p = dot8(v0, v1);
        p += __shfl_xor(p, 1, 64);
        p += __shfl_xor(p, 2, 64);
        p += __shfl_xor(p, 4, 64);
        p += __shfl_xor(p, 8, 64);
        float nm = fmaxf(m_run, p);
        float sc = __expf(m_run - nm);
        float e  = __expf(p - nm);
        l_run = fmaf(l_run, sc, e);
        acc0.x = fmaf(acc0.x, sc, e * v0.x);
        acc0.y = fmaf(acc0.y, sc, e * v0.y);
        acc0.z = fmaf(acc0.z, sc, e * v0.z);
        acc0.w = fmaf(acc0.w, sc, e * v0.w);
        acc1.x = fmaf(acc1.x, sc, e * v1.x);
        acc1.y = fmaf(acc1.y, sc, e * v1.y);
        acc1.z = fmaf(acc1.z, sc, e * v1.z);
        acc1.w = fmaf(acc1.w, sc, e * v1.w);
        m_run = nm;
    };

    Trip A, Bv;

    for (int step = 0; step < STEPS; ++step) {
        // prefetch trip 0 of x under the GRU (x is step-invariant; no LDS dep)
        if (F > 0) load_trip(A, 0);

        // ---- GRU gate rows: threads 0..191, rows 2t and 2t+1 (ILP 2) ----
        if (tid < 192) {
            const int r0 = tid * 2, r1 = r0 + 1;
            float gi0 = bih[r0], gi1 = bih[r1];
            float gh0 = bhh[r0], gh1 = bhh[r1];
            const float4* q4 = (const float4*)s_q;
            const float4* h4 = (const float4*)s_h;
            const uint4* w0 = (const uint4*)(wih_bf + (size_t)r0 * (2 * D));
            const uint4* w1 = (const uint4*)(wih_bf + (size_t)r1 * (2 * D));
#pragma unroll 4
            for (int c = 0; c < 32; ++c) {        // 256 cols of Wih, 8/iter
                uint4 wa = w0[c], wb = w1[c];
                float4 qa = q4[2 * c], qb = q4[2 * c + 1];
                gi0 = fmaf(bflo(wa.x), qa.x, gi0); gi0 = fmaf(bfhi(wa.x), qa.y, gi0);
                gi0 = fmaf(bflo(wa.y), qa.z, gi0); gi0 = fmaf(bfhi(wa.y), qa.w, gi0);
                gi0 = fmaf(bflo(wa.z), qb.x, gi0); gi0 = fmaf(bfhi(wa.z), qb.y, gi0);
                gi0 = fmaf(bflo(wa.w), qb.z, gi0); gi0 = fmaf(bfhi(wa.w), qb.w, gi0);
                gi1 = fmaf(bflo(wb.x), qa.x, gi1); gi1 = fmaf(bfhi(wb.x), qa.y, gi1);
                gi1 = fmaf(bflo(wb.y), qa.z, gi1); gi1 = fmaf(bfhi(wb.y), qa.w, gi1);
                gi1 = fmaf(bflo(wb.z), qb.x, gi1); gi1 = fmaf(bfhi(wb.z), qb.y, gi1);
                gi1 = fmaf(bflo(wb.w), qb.z, gi1); gi1 = fmaf(bfhi(wb.w), qb.w, gi1);
            }
            const uint4* v0 = (const uint4*)(whh_bf + (size_t)r0 * D);
            const uint4* v1 = (const uint4*)(whh_bf + (size_t)r1 * D);
#pragma unroll 4
            for (int c = 0; c < 16; ++c) {        // 128 cols of Whh
                uint4 wa = v0[c], wb = v1[c];
                float4 ha = h4[2 * c], hb = h4[2 * c + 1];
                gh0 = fmaf(bflo(wa.x), ha.x, gh0); gh0 = fmaf(bfhi(wa.x), ha.y, gh0);
                gh0 = fmaf(bflo(wa.y), ha.z, gh0); gh0 = fmaf(bfhi(wa.y), ha.w, gh0);
                gh0 = fmaf(bflo(wa.z), hb.x, gh0); gh0 = fmaf(bfhi(wa.z), hb.y, gh0);
                gh0 = fmaf(bflo(wa.w), hb.z, gh0); gh0 = fmaf(bfhi(wa.w), hb.w, gh0);
                gh1 = fmaf(bflo(wb.x), ha.x, gh1); gh1 = fmaf(bfhi(wb.x), ha.y, gh1);
                gh1 = fmaf(bflo(wb.y), ha.z, gh1); gh1 = fmaf(bfhi(wb.y), ha.w, gh1);
                gh1 = fmaf(bflo(wb.z), hb.x, gh1); gh1 = fmaf(bfhi(wb.z), hb.y, gh1);
                gh1 = fmaf(bflo(wb.w), hb.z, gh1); gh1 = fmaf(bfhi(wb.w), hb.w, gh1);
            }
            s_gi[r0] = gi0; s_gi[r1] = gi1;
            s_gh[r0] = gh0; s_gh[r1] = gh1;
        }
        __syncthreads();
        // ---- GRU epilogue ----
        if (tid < D) {
            const int t = tid;
            float r  = sigmoidf_(s_gi[t] + s_gh[t]);
            float z  = sigmoidf_(s_gi[D + t] + s_gh[D + t]);
            float nn = tanhf(s_gi[2 * D + t] + r * s_gh[2 * D + t]);
            float hn = (1.f - z) * nn + z * s_h[t];
            s_h[t] = hn;
            s_q[t] = hn;                  // q part of q_star
        }
        __syncthreads();

        // ---- flash attention, 16-lane groups, 4 nodes/trip, double-buffered --
        q0 = ((const float4*)s_h)[2 * s];
        q1 = ((const float4*)s_h)[2 * s + 1];
        m_run = -INFINITY; l_run = 0.f;
        acc0 = make_float4(0.f, 0.f, 0.f, 0.f);
        acc1 = make_float4(0.f, 0.f, 0.f, 0.f);

        if (F > 0) {
            int t = 0;
            for (; t + 2 < F; t += 2) {
                load_trip(Bv, t + 1); compute(A);
                load_trip(A,  t + 2); compute(Bv);
            }
            if (t + 2 == F) { load_trip(Bv, t + 1); compute(A); compute(Bv); }
            else            { compute(A); }       // t + 1 == F
        }
        {   // tail: nodes start + g + 16u + 64F (group-uniform predicates)
            const int nt = start + g + (F << 6);
#pragma unroll
            for (int u = 0; u < 4; ++u) {
                const int nd = nt + (u << 4);
                if (nd < end) {
                    const float* p = x + (size_t)nd * D + s * 8;
                    one_node(ld4(p), ld4(p + 4));
                }
            }
        }

        if (s == 0) { sm[g] = m_run; sl[g] = l_run; }
        __syncthreads();

        // ---- combine 16 group partials (every lane, 4-shfl tree) ----
        {
            const float mv = sm[s];
            const float lv = sl[s];
            float M = mv;
            M = fmaxf(M, __shfl_xor(M, 1, 64));
            M = fmaxf(M, __shfl_xor(M, 2, 64));
            M = fmaxf(M, __shfl_xor(M, 4, 64));
            M = fmaxf(M, __shfl_xor(M, 8, 64));
            float term = (mv == -INFINITY) ? 0.f : lv * __expf(mv - M);
            term += __shfl_xor(term, 1, 64);
            term += __shfl_xor(term, 2, 64);
            term += __shfl_xor(term, 4, 64);
            term += __shfl_xor(term, 8, 64);
            const float inv = 1.f / (term + 1e-16f);
            const float fac = (m_run == -INFINITY) ? 0.f : __expf(m_run - M) * inv;
            acc0.x *= fac; acc0.y *= fac; acc0.z *= fac; acc0.w *= fac;
            acc1.x *= fac; acc1.y *= fac; acc1.z *= fac; acc1.w *= fac;
        }
        // ---- sum the 4 groups within each wave (lanes s, s^16, s^32, s^48) --
        acc0.x += __shfl_xor(acc0.x, 16, 64); acc0.y += __shfl_xor(acc0.y, 16, 64);
        acc0.z += __shfl_xor(acc0.z, 16, 64); acc0.w += __shfl_xor(acc0.w, 16, 64);
        acc1.x += __shfl_xor(acc1.x, 16, 64); acc1.y += __shfl_xor(acc1.y, 16, 64);
        acc1.z += __shfl_xor(acc1.z, 16, 64); acc1.w += __shfl_xor(acc1.w, 16, 64);
        acc0.x += __shfl_xor(acc0.x, 32, 64); acc0.y += __shfl_xor(acc0.y, 32, 64);
        acc0.z += __shfl_xor(acc0.z, 32, 64); acc0.w += __shfl_xor(acc0.w, 32, 64);
        acc1.x += __shfl_xor(acc1.x, 32, 64); acc1.y += __shfl_xor(acc1.y, 32, 64);
        acc1.z += __shfl_xor(acc1.z, 32, 64); acc1.w += __shfl_xor(acc1.w, 32, 64);

        const int wv = tid >> 6;          // wave id 0..3
        if ((tid & 63) < 16) {
            float4* dst = (float4*)&rpart[wv][s * 8];
            dst[0] = acc0; dst[1] = acc1;
        }
        __syncthreads();
        if (tid < D) {
            float v = (rpart[0][tid] + rpart[1][tid]) + (rpart[2][tid] + rpart[3][tid]);
            s_q[D + tid] = v;             // r part of q_star (already /L)
        }
        __syncthreads();                  // s_q complete for next GRU / output
    }

    // ---- write q_star row (s_q is exactly [q | r]) ----
    if (tid < 2 * D) out[(size_t)b * (2 * D) + tid] = s_q[tid];
}

// ---------------------------------------------------------------------------
extern "C" void kernel_launch(void* const* d_in, const int* in_sizes, int n_in,
                              void* d_out, int out_size, void* d_ws, size_t ws_size,
                              hipStream_t stream) {
    const float* x    = (const float*)d_in[0];
    const int*   batch= (const int*)d_in[1];
    // d_in[2] = batch_size scalar (fixed at B=512 compile time)
    const float* Wih  = (const float*)d_in[3];
    const float* Whh  = (const float*)d_in[4];
    const float* bih  = (const float*)d_in[5];
    const float* bhh  = (const float*)d_in[6];
    const int n = in_sizes[0] / D;        // 200000

    // workspace: seg (4 KB pad) | wih_bf (192 KB) | whh_bf (96 KB)
    char* ws = (char*)d_ws;
    int* seg = (int*)ws;
    unsigned short* wih_bf = (unsigned short*)(ws + 4096);
    unsigned short* whh_bf = (unsigned short*)(ws + 4096 + (size_t)NW_IH * 2);

    const int total = NW_IH + NW_HH;      // 147456 >= B+1, covers seg too
    k_prep<<<(total + 255) / 256, 256, 0, stream>>>(Wih, Whh, batch, n, wih_bf, whh_bf, seg);
    k_set2set<<<B, 256, 0, stream>>>(x, wih_bf, whh_bf, bih, bhh, seg, (float*)d_out);
}